// Round 16
// baseline (259.262 us; speedup 1.0000x reference)
//
#include <hip/hip_runtime.h>
#include <stdint.h>

// out[b,o,m] = sum_i in[b,i,m] * w[i,o,m]  (complex, fp32)
// B=32, Ci=Co=128, M=64*65=4160. One float2 per complex element.
//
// R16: wave-autonomous W stream. Diagnosis across R2-R15: barrier-synced
// chunk loops are pinned at loaded HBM latency (~3-4us/chunk regardless of
// bytes); throughput = streams x bytes/latency. Fix: the cold W stream is
// staged into WAVE-PRIVATE LDS ring slots with per-wave counted vmcnt and
// is NEVER drained by a barrier; only the small L2-hot A chunk keeps the
// barrier'd double buffer. W lookahead = 4 pairs (4KB/wave in flight;
// 16 waves/CU -> 64KB/CU ~ 2x Little's-law min for 6.3 TB/s).
// Job = 32b x 32o x 16m (acc 32 f2/thread); 1024 exact full jobs
// + last 16 jobs split into 64 quarter-k atomic jobs (pre-zeroed slice).
// All vmcnt waits are exact compile-time constants (see derivation):
// steady pair wait = 8, chunk-top A wait = 2; chunk0 pairs = 6,6;
// chunk nch-2 pairs = 7,6; chunk nch-1: drain 0.

typedef float f2 __attribute__((ext_vector_type(2)));
typedef float f4 __attribute__((ext_vector_type(4)));

#define NB 32
#define CI 128
#define CO 128
#define OTILE 32
#define MODES 4160
#define MPB 16
#define KC 4                       // k per A-chunk (2 W-pairs per chunk)
#define AF2 (KC * NB * MPB / 2)    // 2048 f2 = 16 KB per A buffer
#define WSLOT 128                  // f2 per W slot (2k x 4o x 16m = 1KB)
#define WRING 6

// acc.lo += a.lo*w.lo - a.hi*w.hi ; acc.hi += a.lo*w.hi + a.hi*w.lo
#define CFMA(acc, av, wv)                                                      \
  asm("v_pk_fma_f32 %0, %1, %2, %0 op_sel:[0,0,0] op_sel_hi:[0,1,1]"           \
      : "+v"(acc) : "v"(av), "v"(wv));                                         \
  asm("v_pk_fma_f32 %0, %1, %2, %0 op_sel:[1,1,0] op_sel_hi:[1,0,1] "          \
      "neg_lo:[1,0,0]"                                                         \
      : "+v"(acc) : "v"(av), "v"(wv));

#define VM_WAIT(N) asm volatile("s_waitcnt vmcnt(" #N ")" ::: "memory")
#define SBAR  __builtin_amdgcn_s_barrier()
#define SCHED0 __builtin_amdgcn_sched_barrier(0)

__device__ __forceinline__ void gload16(const f2* g, f2* l) {
    __builtin_amdgcn_global_load_lds(
        (const __attribute__((address_space(1))) uint32_t*)g,
        (__attribute__((address_space(3))) uint32_t*)l, 16, 0, 0);
}

__global__ void zero_tail(f2* __restrict__ Og) {
    // zero modes [4096,4160) for all (b,o): the 16 tail jobs' output (2MB)
    const int tid = blockIdx.x * 256 + threadIdx.x;   // 262144 total
    const int mm = tid & 63;
    const int o  = (tid >> 6) & 127;
    const int b  = tid >> 13;
    Og[(size_t)(b * CO + o) * MODES + 4096 + mm] = (f2)(0.0f);
}

// one W-pair compute: j = pair-in-chunk (0/1), Ab = A buf base, Wsp = W slot
#define PAIRCOMP(Ab, j, Wsp)                                                   \
  _Pragma("unroll")                                                            \
  for (int kk2 = 0; kk2 < 2; ++kk2) {                                          \
    f4 a4[4], w4[4];                                                           \
    _Pragma("unroll")                                                          \
    for (int r = 0; r < 4; ++r)                                                \
      a4[r] = *(const f4*)&(Ab)[(((j)*2 + kk2) * 32 + sb * 4 + r) * 16 + ml2 * 2]; \
    _Pragma("unroll")                                                          \
    for (int q = 0; q < 4; ++q)                                                \
      w4[q] = *(const f4*)&(Wsp)[kk2 * 64 + q * 16 + ml2 * 2];                 \
    __builtin_amdgcn_s_setprio(1);                                             \
    _Pragma("unroll")                                                          \
    for (int r = 0; r < 4; ++r) {                                              \
      const f2 alo = __builtin_shufflevector(a4[r], a4[r], 0, 1);              \
      const f2 ahi = __builtin_shufflevector(a4[r], a4[r], 2, 3);              \
      _Pragma("unroll")                                                        \
      for (int q = 0; q < 4; ++q) {                                            \
        const f2 wlo = __builtin_shufflevector(w4[q], w4[q], 0, 1);            \
        const f2 whi = __builtin_shufflevector(w4[q], w4[q], 2, 3);            \
        CFMA(acc[r][q][0], alo, wlo);                                          \
        CFMA(acc[r][q][1], ahi, whi);                                          \
      }                                                                        \
    }                                                                          \
    __builtin_amdgcn_s_setprio(0);                                             \
  }

#define ISSUE_A(buf)                                                           \
  { gload16(Aad0, Ad0 + (buf) * AF2 * 2); gload16(Aad1, Ad1 + (buf) * AF2 * 2); \
    Aad0 += KC * MODES; Aad1 += KC * MODES; }

#define ISSUE_W(slot)                                                          \
  { gload16(Wad, Wd + (slot) * WSLOT); Wad += 2 * (size_t)CO * MODES; }

__global__ __launch_bounds__(512, 4)
void cmul2d_kernel(const f2* __restrict__ Ig,
                   const f2* __restrict__ Wl,
                   f2* __restrict__ Og) {
    // A: 2 bufs x 2048 f2 (16KB each); W: 8 waves x 6 slots x 128 f2. 80KB.
    __shared__ f2 lds[2 * AF2 * 2 + 8 * WRING * WSLOT];
    f2* Wr = lds + 2 * AF2 * 2;

    const int t   = threadIdx.x;
    const int bid = blockIdx.x;

    int jid, k0, nch; bool tail;
    if (bid < 1024) { jid = bid; k0 = 0; nch = 32; tail = false; }
    else { const int x = bid - 1024;
           jid = 1024 + (x & 15); k0 = (x >> 4) * 32; nch = 8; tail = true; }

    const int m0    = (jid >> 2) * MPB;
    const int obase = (jid & 3) * OTILE;

    const int w = t >> 6, lane = t & 63;
    const int sb = (t >> 3) & 7, ml2 = t & 7;

    // A DMA assignment: wave w handles units idx=2w,2w+1; idx=(kkA<<2)|boct
    const int kkA0 = (w * 2) >> 2,     bo0 = (w * 2) & 3;
    const int kkA1 = (w * 2 + 1) >> 2, bo1 = (w * 2 + 1) & 3;
    const int ls = lane >> 3, lm = lane & 7;
    const f2* Aad0 = Ig + (size_t)((bo0 * 8 + ls) * CI + k0 + kkA0) * MODES + m0 + lm * 2;
    const f2* Aad1 = Ig + (size_t)((bo1 * 8 + ls) * CI + k0 + kkA1) * MODES + m0 + lm * 2;
    const f2* Wad  = Wl + (size_t)((k0 + (lane >> 5)) * CO + obase + w * 4 + ((lane >> 3) & 3)) * MODES + m0 + lm * 2;

    f2* Ad0 = lds + (kkA0 * 32 + bo0 * 8) * 16;   // + buf*4096 f2
    f2* Ad1 = lds + (kkA1 * 32 + bo1 * 8) * 16;
    f2* Wd  = Wr + w * (WRING * WSLOT);           // wave-private ring

    f2 acc[4][4][2];
#pragma unroll
    for (int r = 0; r < 4; ++r)
#pragma unroll
        for (int q = 0; q < 4; ++q) { acc[r][q][0] = (f2)(0.0f); acc[r][q][1] = (f2)(0.0f); }

    // ---- prologue: A(0); W(0..3); A-wait; barrier; A(1) ----
    ISSUE_A(0);
    ISSUE_W(0); ISSUE_W(1); ISSUE_W(2); ISSUE_W(3);
    VM_WAIT(4);  SCHED0;      // A(0) landed (4 newest = W0..3)
    SBAR;
    ISSUE_A(1);

    // ---- chunk 0 (buf0, slots 0,1; waits 6,6; issue W4,W5) ----
    ISSUE_W(4);  VM_WAIT(6);  SCHED0;  PAIRCOMP(lds, 0, Wd + 0 * WSLOT);
    ISSUE_W(5);  VM_WAIT(6);  SCHED0;  PAIRCOMP(lds, 1, Wd + 1 * WSLOT);

    int sb6 = 2;                 // slot base of chunk c (cycles 2,4,0,...)
#pragma unroll 1
    for (int c = 1; c <= nch - 3; ++c) {
        VM_WAIT(2);  SCHED0;     // A(c) landed (2 newest = this wave's W's)
        SBAR;                    // all waves have A(c); buf (c+1)&1 free
        ISSUE_A((c + 1) & 1);
        const f2* Ab = lds + (c & 1) * (AF2 * 2);
        const int is0 = (sb6 >= 2) ? sb6 - 2 : 4;      // (sb6+4)%6
        ISSUE_W(is0);      VM_WAIT(8);  SCHED0;  PAIRCOMP(Ab, 0, Wd + sb6 * WSLOT);
        ISSUE_W(is0 + 1);  VM_WAIT(8);  SCHED0;  PAIRCOMP(Ab, 1, Wd + (sb6 + 1) * WSLOT);
        sb6 = (sb6 == 4) ? 0 : sb6 + 2;
    }

    // ---- chunk nch-2 (no W issues; waits 7,6) ----
    VM_WAIT(2);  SCHED0;  SBAR;
    ISSUE_A((nch - 1) & 1);
    {
        const f2* Ab = lds + ((nch - 2) & 1) * (AF2 * 2);
        VM_WAIT(7);  SCHED0;  PAIRCOMP(Ab, 0, Wd + sb6 * WSLOT);
        VM_WAIT(6);  SCHED0;  PAIRCOMP(Ab, 1, Wd + (sb6 + 1) * WSLOT);
        sb6 = (sb6 == 4) ? 0 : sb6 + 2;
    }

    // ---- chunk nch-1 (full drain once; no waits inside) ----
    VM_WAIT(0);  SCHED0;  SBAR;
    {
        const f2* Ab = lds + ((nch - 1) & 1) * (AF2 * 2);
        PAIRCOMP(Ab, 0, Wd + sb6 * WSLOT);
        PAIRCOMP(Ab, 1, Wd + (sb6 + 1) * WSLOT);
    }

    // ---- epilogue: f4 stores (128B runs); tail blocks atomicAdd ----
#pragma unroll
    for (int r = 0; r < 4; ++r) {
        const int b = sb * 4 + r;
#pragma unroll
        for (int q = 0; q < 4; ++q) {
            const int o = obase + w * 4 + q;
            const size_t pos = (size_t)(b * CO + o) * MODES + m0 + ml2 * 2;
            f4 v = { acc[r][q][0].x, acc[r][q][0].y,
                     acc[r][q][1].x, acc[r][q][1].y };
            if (!tail) {
                *(f4*)&Og[pos] = v;
            } else {
                float* p = (float*)&Og[pos];
                atomicAdd(p + 0, v.x); atomicAdd(p + 1, v.y);
                atomicAdd(p + 2, v.z); atomicAdd(p + 3, v.w);
            }
        }
    }
}

extern "C" void kernel_launch(void* const* d_in, const int* in_sizes, int n_in,
                              void* d_out, int out_size, void* d_ws, size_t ws_size,
                              hipStream_t stream) {
    const f2* I = (const f2*)d_in[0];
    const f2* W = (const f2*)d_in[1];
    f2* O = (f2*)d_out;
    zero_tail<<<1024, 256, 0, stream>>>(O);           // zero tail slice
    cmul2d_kernel<<<1088, 512, 0, stream>>>(I, W, O); // 1024 full + 64 quarters
}